// Round 1
// baseline (613.376 us; speedup 1.0000x reference)
//
#include <hip/hip_runtime.h>
#include <hip/hip_bf16.h>

typedef __attribute__((ext_vector_type(8)))  __bf16 bf16x8;
typedef __attribute__((ext_vector_type(16))) float  f32x16;

#define SDIM 49
#define NDIM 1024
#define CDIM 384
#define DDIM 512
#define DMC  64

// ---------------------------------------------------------------------------
// pack: x [N,C,S] (f32) + m [N,64] + c [N,64]  ->  bf16 [S, N, 512] row-major
// thread d of block j handles column d for all 49 spatial positions.
// Reads: 49 contiguous floats per thread (L1-cached strided pattern).
// Writes: per s, 512 consecutive bf16 = 1 KB coalesced.
// ---------------------------------------------------------------------------
__global__ __launch_bounds__(512) void pack_kernel(
    const float* __restrict__ xloc, const float* __restrict__ mv,
    const float* __restrict__ cv,   __hip_bfloat16* __restrict__ dst)
{
    const int j = blockIdx.x;
    const int d = threadIdx.x;
    float vals[SDIM];
    if (d < CDIM) {
        const float* p = xloc + ((size_t)j * CDIM + d) * SDIM;
        #pragma unroll
        for (int s = 0; s < SDIM; ++s) vals[s] = p[s];
    } else if (d < CDIM + DMC) {
        float v = mv[j * DMC + (d - CDIM)];
        #pragma unroll
        for (int s = 0; s < SDIM; ++s) vals[s] = v;
    } else {
        float v = cv[j * DMC + (d - CDIM - DMC)];
        #pragma unroll
        for (int s = 0; s < SDIM; ++s) vals[s] = v;
    }
    #pragma unroll
    for (int s = 0; s < SDIM; ++s)
        dst[((size_t)s * NDIM + j) * DDIM + d] = __float2bfloat16(vals[s]);
}

__global__ void fpack_kernel(const float* __restrict__ f,
                             __hip_bfloat16* __restrict__ dst, int n)
{
    int i = blockIdx.x * blockDim.x + threadIdx.x;
    if (i < n) dst[i] = __float2bfloat16(f[i]);
}

// passthrough copies of x_prev and x into d_out[1..], plus zero-init of loss.
__global__ void copy_kernel(const float* __restrict__ a, const float* __restrict__ b,
                            float* __restrict__ out, int sz)
{
    if (blockIdx.x == 0 && threadIdx.x == 0) out[0] = 0.0f;
    const size_t stride = (size_t)gridDim.x * blockDim.x;
    const size_t total  = 2ull * (size_t)sz;
    for (size_t i = (size_t)blockIdx.x * blockDim.x + threadIdx.x; i < total; i += stride) {
        float v = (i < (size_t)sz) ? a[i] : b[i - sz];
        out[1 + i] = v;
    }
}

// ---------------------------------------------------------------------------
// Fused logits + online logsumexp + diag + loss accumulate.
// grid = 49 s * 2 qsets * 8 rowblocks = 784 blocks of 256 threads (4 waves).
// Each wave owns 32 query rows; Q fragments live in registers (qf[32]);
// keys streamed 64 at a time directly from L2 (no LDS in the hot loop).
// MFMA 32x32x16 bf16; D-layout: col=lane&31, row=(reg&3)+8*(reg>>2)+4*(lane>>5).
// A/B operand layout: row(col)=lane&31, k=(lane>>5)*8 + i  (8 contiguous bf16).
// ---------------------------------------------------------------------------
__global__ __launch_bounds__(256, 2) void loss_kernel(
    const __hip_bfloat16* __restrict__ Fm,   // [N,512]
    const __hip_bfloat16* __restrict__ Km,   // [S,N,512]  keys (pos)
    const __hip_bfloat16* __restrict__ Qm,   // [S,N,512]  queries (pred2)
    float* __restrict__ out)
{
    const int bid = blockIdx.x;
    const int gid = (bid & 7) * 98 + (bid >> 3);   // XCD-chunked, bijective (784%8==0)
    const int s      = gid >> 4;
    const int rem    = gid & 15;
    const int qset   = rem >> 3;
    const int rowblk = rem & 7;

    const int tid  = threadIdx.x;
    const int lane = tid & 63;
    const int wid  = tid >> 6;          // 0..3
    const int r31  = lane & 31;
    const int hi   = lane >> 5;

    const int qbase = rowblk * 128 + wid * 32;   // wave's first query row

    const __bf16* Q = (const __bf16*)(qset ? (Qm + (size_t)s * NDIM * DDIM) : Fm);
    const __bf16* K = (const __bf16*)(Km + (size_t)s * NDIM * DDIM);

    // persistent Q fragments: 32 k-steps x 8 bf16 = 128 VGPRs
    bf16x8 qf[32];
    {
        const __bf16* p = Q + (size_t)(qbase + r31) * DDIM + hi * 8;
        #pragma unroll
        for (int kk = 0; kk < 32; ++kk) qf[kk] = *(const bf16x8*)(p + kk * 16);
    }

    // diag bookkeeping (uniform per wave except lane validity)
    const int b32     = qbase >> 5;
    const int kb_diag = b32 >> 1;
    const int c_diag  = b32 & 1;
    const int tdiag   = (r31 & 3) | ((r31 >> 3) << 2);
    const bool dvalid = (((r31 >> 2) & 1) == hi);

    float m_[16], s_[16];
    #pragma unroll
    for (int t = 0; t < 16; ++t) { m_[t] = -3.0e38f; s_[t] = 0.0f; }
    float diag_acc = 0.0f;

    for (int kb = 0; kb < 16; ++kb) {
        const __bf16* kp0 = K + (size_t)(kb * 64 + r31) * DDIM + hi * 8;
        const __bf16* kp1 = kp0 + 32 * DDIM;
        f32x16 a0 = {};
        f32x16 a1 = {};
        #pragma unroll
        for (int kk = 0; kk < 32; ++kk) {
            bf16x8 b0v = *(const bf16x8*)(kp0 + kk * 16);
            bf16x8 b1v = *(const bf16x8*)(kp1 + kk * 16);
            a0 = __builtin_amdgcn_mfma_f32_32x32x16_bf16(qf[kk], b0v, a0, 0, 0, 0);
            a1 = __builtin_amdgcn_mfma_f32_32x32x16_bf16(qf[kk], b1v, a1, 0, 0, 0);
        }
        // online logsumexp update: each reg t is one query row, 2 new cols
        #pragma unroll
        for (int t = 0; t < 16; ++t) {
            float v0 = a0[t], v1 = a1[t];
            float nm = fmaxf(m_[t], fmaxf(v0, v1));
            s_[t] = s_[t] * __expf(m_[t] - nm) + __expf(v0 - nm) + __expf(v1 - nm);
            m_[t] = nm;
        }
        if (kb == kb_diag && dvalid) {
            #pragma unroll
            for (int t = 0; t < 16; ++t)
                if (t == tdiag) diag_acc += (c_diag ? a1[t] : a0[t]);
        }
    }

    // combine (m,s) across the 32 lanes of each half -> per-row lse
    float lse_part = 0.0f;
    #pragma unroll
    for (int t = 0; t < 16; ++t) {
        float m = m_[t], ss = s_[t];
        #pragma unroll
        for (int off = 1; off < 32; off <<= 1) {
            float mo = __shfl_xor(m, off, 64);
            float so = __shfl_xor(ss, off, 64);
            float nm = fmaxf(m, mo);
            ss = ss * __expf(m - nm) + so * __expf(mo - nm);
            m = nm;
        }
        if (r31 == 0) lse_part += m + __logf(ss);
    }

    // block contribution: sum over rows of (lse - diag)
    float x = lse_part - diag_acc;
    #pragma unroll
    for (int off = 32; off >= 1; off >>= 1) x += __shfl_xor(x, off, 64);

    __shared__ float red[4];
    if (lane == 0) red[wid] = x;
    __syncthreads();
    if (tid == 0) {
        float tot = red[0] + red[1] + red[2] + red[3];
        atomicAdd(out, tot * (1.0f / (SDIM * NDIM)));
    }
}

extern "C" void kernel_launch(void* const* d_in, const int* in_sizes, int n_in,
                              void* d_out, int out_size, void* d_ws, size_t ws_size,
                              hipStream_t stream)
{
    (void)in_sizes; (void)n_in; (void)out_size; (void)ws_size;
    const float* f  = (const float*)d_in[0];
    const float* x  = (const float*)d_in[1];
    const float* xp = (const float*)d_in[2];
    const float* mt = (const float*)d_in[3];
    const float* mp = (const float*)d_in[4];
    const float* ct = (const float*)d_in[5];
    const float* cp = (const float*)d_in[6];
    float* out = (float*)d_out;

    char* ws = (char*)d_ws;
    const size_t packBytes = (size_t)SDIM * NDIM * DDIM * 2;  // 51.4 MB
    __hip_bfloat16* Km = (__hip_bfloat16*)ws;
    __hip_bfloat16* Qm = (__hip_bfloat16*)(ws + packBytes);
    __hip_bfloat16* Fm = (__hip_bfloat16*)(ws + 2 * packBytes);

    pack_kernel<<<NDIM, 512, 0, stream>>>(xp, mp, cp, Km);   // pos  (keys)
    pack_kernel<<<NDIM, 512, 0, stream>>>(x,  mt, ct, Qm);   // pred2 (queries)
    fpack_kernel<<<(NDIM * DDIM + 255) / 256, 256, 0, stream>>>(f, Fm, NDIM * DDIM);

    const int sz = NDIM * CDIM * SDIM;
    copy_kernel<<<2048, 256, 0, stream>>>(xp, x, out, sz);

    loss_kernel<<<784, 256, 0, stream>>>(Fm, Km, Qm, out);
}

// Round 2
// 336.985 us; speedup vs baseline: 1.8202x; 1.8202x over previous
//
#include <hip/hip_runtime.h>
#include <hip/hip_bf16.h>

typedef __attribute__((ext_vector_type(8)))  __bf16 bf16x8;
typedef __attribute__((ext_vector_type(16))) float  f32x16;

#define SDIM 49
#define NDIM 1024
#define CDIM 384
#define DDIM 512
#define DMC  64

#define KEYS 128            // keys per kb tile
#define DC   128            // d per stage chunk
#define NKB  (NDIM/KEYS)    // 8
#define NDC  (DDIM/DC)      // 4

__device__ __forceinline__ void gload16(const void* g, void* l) {
    __builtin_amdgcn_global_load_lds((const __attribute__((address_space(1))) void*)g,
                                     (__attribute__((address_space(3))) void*)l, 16, 0, 0);
}

// ---------------------------------------------------------------------------
// pack: x [N,C,S] (f32) + m [N,64] + c [N,64]  ->  bf16 [S, N, 512] row-major
// ---------------------------------------------------------------------------
__global__ __launch_bounds__(512) void pack_kernel(
    const float* __restrict__ xloc, const float* __restrict__ mv,
    const float* __restrict__ cv,   __hip_bfloat16* __restrict__ dst)
{
    const int j = blockIdx.x;
    const int d = threadIdx.x;
    float vals[SDIM];
    if (d < CDIM) {
        const float* p = xloc + ((size_t)j * CDIM + d) * SDIM;
        #pragma unroll
        for (int s = 0; s < SDIM; ++s) vals[s] = p[s];
    } else if (d < CDIM + DMC) {
        float v = mv[j * DMC + (d - CDIM)];
        #pragma unroll
        for (int s = 0; s < SDIM; ++s) vals[s] = v;
    } else {
        float v = cv[j * DMC + (d - CDIM - DMC)];
        #pragma unroll
        for (int s = 0; s < SDIM; ++s) vals[s] = v;
    }
    #pragma unroll
    for (int s = 0; s < SDIM; ++s)
        dst[((size_t)s * NDIM + j) * DDIM + d] = __float2bfloat16(vals[s]);
}

__global__ void fpack_kernel(const float* __restrict__ f,
                             __hip_bfloat16* __restrict__ dst, int n)
{
    int i = blockIdx.x * blockDim.x + threadIdx.x;
    if (i < n) dst[i] = __float2bfloat16(f[i]);
}

// ---------------------------------------------------------------------------
// Fused GEMM + online logsumexp + diag, m97-style 2-phase LDS staging.
// grid = 49 s * 16 rowblocks = 784 blocks of 256 threads (4 waves, 2x2).
// Block tile: 128 q-rows x 128 keys; D chunked by 128 (8 kk of K=16).
// LDS 64KB: Q[128][256B] @0, K[128][256B] @32KB; XOR-swizzle (row&15)<<4
// applied on the GLOBAL source (linear global_load_lds dest) and on ds_read.
// MFMA 32x32x16 bf16, C/D: col=lane&31, row=(reg&3)+8*(reg>>2)+4*(lane>>5).
// ---------------------------------------------------------------------------
__global__ __launch_bounds__(256, 2) void loss_kernel(
    const __hip_bfloat16* __restrict__ Fm,   // [N,512]
    const __hip_bfloat16* __restrict__ Km,   // [S,N,512]  keys (pos)
    const __hip_bfloat16* __restrict__ Qm,   // [S,N,512]  queries (pred2)
    float* __restrict__ out)
{
    __shared__ __attribute__((aligned(16))) char sm[65536];

    const int bid = blockIdx.x;
    const int gid = (bid & 7) * 98 + (bid >> 3);   // XCD-chunked, bijective
    const int s      = gid >> 4;
    const int rowblk = gid & 15;

    const int tid  = threadIdx.x;
    const int lane = tid & 63;
    const int wid  = tid >> 6;
    const int r31  = lane & 31;
    const int hi   = lane >> 5;
    const int wr   = wid >> 1;
    const int wc   = wid & 1;

    const char* Qg = (const char*)((rowblk < 8)
        ? (Fm + (size_t)rowblk * 128 * DDIM)
        : (Qm + ((size_t)s * NDIM + (size_t)(rowblk - 8) * 128) * DDIM));
    const char* Kg = (const char*)(Km + (size_t)s * NDIM * DDIM);
    const int kb_diag = rowblk & 7;

    // staging constants: thread covers rows trow+16*it, 16B slot (tid&15),
    // source pre-swizzled so LDS[o] = G[row*1024 + dc*256 + ((o&255)^((row&15)<<4))]
    const int trow = tid >> 4;                      // 0..15
    const int tswz = ((tid & 15) ^ trow) << 4;      // constant per thread

    // compute-side constants
    const int xorv = (r31 & 15) << 4;
    const unsigned aoff = (unsigned)(wr * 64 + r31) * 256u;
    const unsigned boff = 32768u + (unsigned)(wc * 64 + r31) * 256u;

    float m_[2][16], s_[2][16];
    #pragma unroll
    for (int f = 0; f < 2; ++f)
        #pragma unroll
        for (int r = 0; r < 16; ++r) { m_[f][r] = -3.0e38f; s_[f][r] = 0.0f; }
    float diag_acc = 0.0f;

    f32x16 acc00{}, acc01{}, acc10{}, acc11{};

    // stage issue for linear iter it2 = kb*4+dc
    auto stage = [&](int it2) {
        const int kb = it2 >> 2, dc = it2 & 3;
        const char* qs = Qg + (size_t)trow * 1024 + dc * 256 + tswz;
        const char* ks = Kg + (size_t)(kb * KEYS + trow) * 1024 + dc * 256 + tswz;
        char* ld = sm + tid * 16;
        #pragma unroll
        for (int it = 0; it < 8; ++it) {
            gload16(qs + it * 16384, ld + it * 4096);
            gload16(ks + it * 16384, ld + 32768 + it * 4096);
        }
    };

    stage(0);

    for (int it2 = 0; it2 < NKB * NDC; ++it2) {
        asm volatile("s_waitcnt vmcnt(0)" ::: "memory");
        __syncthreads();                 // staged tile visible to all waves
        #pragma unroll
        for (int kk = 0; kk < 8; ++kk) {
            const int idx = (kk * 32 + hi * 16) ^ xorv;
            bf16x8 a0 = *(const bf16x8*)(sm + (aoff + idx));
            bf16x8 a1 = *(const bf16x8*)(sm + (aoff + 8192 + idx));
            bf16x8 b0 = *(const bf16x8*)(sm + (boff + idx));
            bf16x8 b1 = *(const bf16x8*)(sm + (boff + 8192 + idx));
            acc00 = __builtin_amdgcn_mfma_f32_32x32x16_bf16(a0, b0, acc00, 0, 0, 0);
            acc01 = __builtin_amdgcn_mfma_f32_32x32x16_bf16(a0, b1, acc01, 0, 0, 0);
            acc10 = __builtin_amdgcn_mfma_f32_32x32x16_bf16(a1, b0, acc10, 0, 0, 0);
            acc11 = __builtin_amdgcn_mfma_f32_32x32x16_bf16(a1, b1, acc11, 0, 0, 0);
        }
        __syncthreads();                 // all waves done reading sm
        if (it2 + 1 < NKB * NDC) stage(it2 + 1);  // async loads overlap LSE below

        if ((it2 & 3) == 3) {
            const int kb = it2 >> 2;
            // online LSE update: reg r of frag-row f is one q-row, 2 cols (fc 0/1)
            #pragma unroll
            for (int r = 0; r < 16; ++r) {
                {
                    float v0 = acc00[r], v1 = acc01[r];
                    float nm = fmaxf(m_[0][r], fmaxf(v0, v1));
                    s_[0][r] = s_[0][r] * __expf(m_[0][r] - nm) + __expf(v0 - nm) + __expf(v1 - nm);
                    m_[0][r] = nm;
                }
                {
                    float v0 = acc10[r], v1 = acc11[r];
                    float nm = fmaxf(m_[1][r], fmaxf(v0, v1));
                    s_[1][r] = s_[1][r] * __expf(m_[1][r] - nm) + __expf(v0 - nm) + __expf(v1 - nm);
                    m_[1][r] = nm;
                }
            }
            if (kb == kb_diag && wr == wc && hi == ((r31 >> 2) & 1)) {
                const int regd = (r31 & 3) | ((r31 >> 3) << 2);
                #pragma unroll
                for (int r = 0; r < 16; ++r)
                    if (r == regd) diag_acc += acc00[r] + acc11[r];
            }
            acc00 = f32x16{}; acc01 = f32x16{}; acc10 = f32x16{}; acc11 = f32x16{};
        }
    }

    // ---- combine (m,s): intra-wave over 32 lanes (64 cols), then cross-wave
    __syncthreads();                      // compute done, sm reusable
    float2* part = (float2*)sm;
    float msm = 0.0f, mss = 0.0f;
    #pragma unroll
    for (int f = 0; f < 2; ++f)
        #pragma unroll
        for (int r = 0; r < 16; ++r) {
            float m = m_[f][r], ss = s_[f][r];
            #pragma unroll
            for (int off = 1; off < 32; off <<= 1) {
                float mo = __shfl_xor(m, off, 64);
                float so = __shfl_xor(ss, off, 64);
                float nm = fmaxf(m, mo);
                ss = ss * __expf(m - nm) + so * __expf(mo - nm);
                m = nm;
            }
            if (r31 == f * 16 + r) { msm = m; mss = ss; }
        }
    {
        const int rg = r31 & 15;
        const int srow = wr * 64 + (r31 >> 4) * 32 + (rg & 3) + 8 * (rg >> 2) + 4 * hi;
        part[srow * 2 + wc] = make_float2(msm, mss);
    }
    __syncthreads();

    float v = 0.0f;
    if (tid < 128) {
        float2 p0 = part[tid * 2], p1 = part[tid * 2 + 1];
        float nm = fmaxf(p0.x, p1.x);
        float S = p0.y * __expf(p0.x - nm) + p1.y * __expf(p1.x - nm);
        v = nm + __logf(S);
    }
    float tot = v - diag_acc;
    #pragma unroll
    for (int off = 1; off < 64; off <<= 1) tot += __shfl_xor(tot, off, 64);
    float* red = (float*)(sm + 2048);
    if (lane == 0) red[wid] = tot;
    __syncthreads();
    if (tid == 0)
        atomicAdd(out, (red[0] + red[1] + red[2] + red[3]) * (1.0f / (SDIM * NDIM)));
}

extern "C" void kernel_launch(void* const* d_in, const int* in_sizes, int n_in,
                              void* d_out, int out_size, void* d_ws, size_t ws_size,
                              hipStream_t stream)
{
    (void)in_sizes; (void)n_in; (void)out_size; (void)ws_size;
    const float* f  = (const float*)d_in[0];
    const float* x  = (const float*)d_in[1];
    const float* xp = (const float*)d_in[2];
    const float* mt = (const float*)d_in[3];
    const float* mp = (const float*)d_in[4];
    const float* ct = (const float*)d_in[5];
    const float* cp = (const float*)d_in[6];
    float* out = (float*)d_out;

    char* ws = (char*)d_ws;
    const size_t packBytes = (size_t)SDIM * NDIM * DDIM * 2;  // 51.4 MB
    __hip_bfloat16* Km = (__hip_bfloat16*)ws;
    __hip_bfloat16* Qm = (__hip_bfloat16*)(ws + packBytes);
    __hip_bfloat16* Fm = (__hip_bfloat16*)(ws + 2 * packBytes);

    hipMemsetAsync(out, 0, sizeof(float), stream);

    pack_kernel<<<NDIM, 512, 0, stream>>>(xp, mp, cp, Km);   // pos  (keys)
    pack_kernel<<<NDIM, 512, 0, stream>>>(x,  mt, ct, Qm);   // pred2 (queries)
    fpack_kernel<<<(NDIM * DDIM + 255) / 256, 256, 0, stream>>>(f, Fm, NDIM * DDIM);

    const size_t szB = (size_t)NDIM * CDIM * SDIM * sizeof(float);
    hipMemcpyAsync(out + 1, xp, szB, hipMemcpyDeviceToDevice, stream);
    hipMemcpyAsync(out + 1 + (size_t)NDIM * CDIM * SDIM, x, szB,
                   hipMemcpyDeviceToDevice, stream);

    loss_kernel<<<784, 256, 0, stream>>>(Fm, Km, Qm, out);
}